// Round 1
// baseline (230.188 us; speedup 1.0000x reference)
//
#include <hip/hip_runtime.h>
#include <hip/hip_bf16.h>
#include <math.h>

// out[b,s,d] = x[b,s,d] + enc(s,d)
// enc(s,d) = even(d) ? sin(s * 10000^(-d/D)) : cos(s * 10000^(-d/D))
// x: fp32 [B=8, S=4096, D=1024]. Memory-bound streaming add.
//
// Strategy: one thread per (s, d-group-of-4). Compute the 4 enc values once
// (they're batch-invariant), then loop over B doing coalesced float4
// load-add-store. Transcendental cost amortized 8x and hidden under HBM.

#define S_LEN 4096
#define D_LEN 1024

__global__ __launch_bounds__(256) void pe_add_kernel(
    const float* __restrict__ x, float* __restrict__ out, int B) {
    const int s   = blockIdx.x;           // 0..4095
    const int tid = threadIdx.x;          // 0..255
    const int d0  = tid << 2;             // 4 consecutive dims

    const float sf = (float)s;
    // angle = s * 10000^(-d/D) = s * exp(d * (-ln(10000)/D))
    const float c = -9.210340371976184f / (float)D_LEN;  // -ln(10000)/1024

    float enc0, enc1, enc2, enc3;
    {
        float a0 = sf * expf((float)(d0 + 0) * c);
        float a1 = sf * expf((float)(d0 + 1) * c);
        float a2 = sf * expf((float)(d0 + 2) * c);
        float a3 = sf * expf((float)(d0 + 3) * c);
        // d0 is a multiple of 4: dims d0,d0+2 even -> sin; d0+1,d0+3 odd -> cos
        enc0 = sinf(a0);
        enc1 = cosf(a1);
        enc2 = sinf(a2);
        enc3 = cosf(a3);
    }

    size_t base = (size_t)s * D_LEN + (size_t)d0;
    const size_t bstride = (size_t)S_LEN * D_LEN;

    #pragma unroll
    for (int b = 0; b < 8; ++b) {
        if (b >= B) break;
        const float4* px = (const float4*)(x + base + (size_t)b * bstride);
        float4 v = *px;
        v.x += enc0;
        v.y += enc1;
        v.z += enc2;
        v.w += enc3;
        *(float4*)(out + base + (size_t)b * bstride) = v;
    }
}

extern "C" void kernel_launch(void* const* d_in, const int* in_sizes, int n_in,
                              void* d_out, int out_size, void* d_ws, size_t ws_size,
                              hipStream_t stream) {
    const float* x = (const float*)d_in[0];
    float* out = (float*)d_out;
    const int B = in_sizes[0] / (S_LEN * D_LEN);  // = 8

    dim3 grid(S_LEN);        // one block per sequence position
    dim3 block(D_LEN / 4);   // 256 threads, one float4 each
    pe_add_kernel<<<grid, block, 0, stream>>>(x, out, B);
}